// Round 5
// baseline (476.405 us; speedup 1.0000x reference)
//
#include <hip/hip_runtime.h>

#define IN_DIM 256   // K of the fused GEMM; also combined hidden (128 homo + 128 het)

typedef __attribute__((ext_vector_type(8))) short short8;
typedef __attribute__((ext_vector_type(4))) float f32x4;
typedef unsigned int uint;
typedef unsigned short ushort;

__device__ __forceinline__ ushort f2bf(float x) {
    uint u = __float_as_uint(x);
    u += 0x7FFFu + ((u >> 16) & 1u);   // round-to-nearest-even
    return (ushort)(u >> 16);
}

// ---------- CSR build ----------
__global__ void count_kernel(const int* __restrict__ dst, int* __restrict__ cnt, int E) {
    int e = blockIdx.x * 256 + threadIdx.x;
    if (e < E) atomicAdd(&cnt[dst[e]], 1);
}

__global__ __launch_bounds__(256) void block_sum_kernel(const int* __restrict__ cnt,
                                                        int* __restrict__ bsum, int N) {
    __shared__ int red[256];
    int base = blockIdx.x * 1024;
    int s = 0;
    for (int i = threadIdx.x; i < 1024; i += 256) {
        int idx = base + i;
        if (idx < N) s += cnt[idx];
    }
    red[threadIdx.x] = s;
    __syncthreads();
    for (int d = 128; d > 0; d >>= 1) {
        if (threadIdx.x < d) red[threadIdx.x] += red[threadIdx.x + d];
        __syncthreads();
    }
    if (threadIdx.x == 0) bsum[blockIdx.x] = red[0];
}

__global__ __launch_bounds__(1024) void scan_sums_kernel(int* __restrict__ bsum, int B) {
    __shared__ int sh[1024];
    int t = threadIdx.x;
    sh[t] = (t < B) ? bsum[t] : 0;
    __syncthreads();
    for (int d = 1; d < 1024; d <<= 1) {
        int v = (t >= d) ? sh[t - d] : 0;
        __syncthreads();
        sh[t] += v;
        __syncthreads();
    }
    if (t < B) bsum[t] = (t == 0) ? 0 : sh[t - 1];
}

// Phase 3: offsets + cur(=off copy, for fill) + dinv
__global__ __launch_bounds__(256) void scan_out_kernel(const int* __restrict__ cnt,
                                                       const int* __restrict__ bsum,
                                                       int* __restrict__ off,
                                                       int* __restrict__ cur,
                                                       float* __restrict__ dinv,
                                                       int N, int E) {
    __shared__ int wsum[4];
    int lane = threadIdx.x & 63, wid = threadIdx.x >> 6;
    int idx = blockIdx.x * 1024 + threadIdx.x * 4;
    int c[4];
    int s = 0;
#pragma unroll
    for (int j = 0; j < 4; ++j) {
        c[j] = (idx + j < N) ? cnt[idx + j] : 0;
        s += c[j];
    }
    int incl = s;
#pragma unroll
    for (int d = 1; d < 64; d <<= 1) {
        int v = __shfl_up(incl, d);
        if (lane >= d) incl += v;
    }
    if (lane == 63) wsum[wid] = incl;
    __syncthreads();
    int woff = 0;
    for (int i = 0; i < 4; ++i) woff += (i < wid) ? wsum[i] : 0;
    int excl = bsum[blockIdx.x] + woff + incl - s;
#pragma unroll
    for (int j = 0; j < 4; ++j) {
        if (idx + j < N) {
            off[idx + j] = excl;
            cur[idx + j] = excl;
            dinv[idx + j] = rsqrtf((float)(c[j] + 1));  // +1 self loop
        }
        excl += c[j];
    }
    if (blockIdx.x == 0 && threadIdx.x == 0) off[N] = E;
}

// fill: cur pre-initialized to off -> atomic returns the csr slot directly
__global__ void fill_kernel(const int* __restrict__ ei, int* __restrict__ cur,
                            int* __restrict__ csr, int E) {
    int e = blockIdx.x * 256 + threadIdx.x;
    if (e < E) {
        int s = ei[e];
        int d = ei[E + e];
        int p = atomicAdd(&cur[d], 1);
        csr[p] = s;
    }
}

// ---------- W prep (pair-permuted: out col 2c = homo c, 2c+1 = het c) ----------
__global__ void wprep_kernel(const float* __restrict__ Wh, const float* __restrict__ Wt,
                             ushort* __restrict__ wT) {
    int pc = blockIdx.x;   // permuted output col 0..255
    int k = threadIdx.x;   // 0..255
    const float* W = (pc & 1) ? Wt : Wh;
    wT[pc * 256 + k] = f2bf(W[(size_t)k * 128 + (pc >> 1)]);
}

__global__ void bias_perm_kernel(const float* __restrict__ bh, const float* __restrict__ bt,
                                 float* __restrict__ pb) {
    int pc = threadIdx.x;
    pb[pc] = (pc & 1) ? bt[pc >> 1] : bh[pc >> 1];
}

// WfB[col][k] = bf16(Wf[k][col])
__global__ void wfb_kernel(const float* __restrict__ Wf, ushort* __restrict__ WfB) {
    int col = blockIdx.x;   // 0..63
    int k = threadIdx.x;    // 0..127
    WfB[col * 128 + k] = f2bf(Wf[(size_t)k * 64 + col]);
}

// ---------- MFMA GEMM -> column-sliced y: y[slice][n][32], slice = pc>>5 ----------
__global__ __launch_bounds__(512) void gemm_kernel(const float* __restrict__ x,
                                                   const ushort* __restrict__ wT,
                                                   const float* __restrict__ dinv,
                                                   ushort* __restrict__ y, int N) {
    __shared__ short As[128 * 64];   // 16 KB
    __shared__ short Bs[256 * 64];   // 32 KB
    int tid = threadIdx.x;
    int lane = tid & 63, wid = tid >> 6;
    int wr = wid >> 2, wc = wid & 3;
    int rowBase = blockIdx.x * 128;

    f32x4 acc[4][4];
#pragma unroll
    for (int a = 0; a < 4; ++a)
#pragma unroll
        for (int b = 0; b < 4; ++b) acc[a][b] = (f32x4){0.f, 0.f, 0.f, 0.f};

    for (int k0 = 0; k0 < IN_DIM; k0 += 64) {
        __syncthreads();
#pragma unroll
        for (int r = 0; r < 2; ++r) {
            int id = tid + r * 512;
            int m = id >> 3, kc = id & 7;
            int gr = rowBase + m; if (gr >= N) gr = N - 1;
            const float* src = x + (size_t)gr * IN_DIM + k0 + kc * 8;
            float4 v0 = *(const float4*)src;
            float4 v1 = *(const float4*)(src + 4);
            short8 pk;
            pk[0] = (short)f2bf(v0.x); pk[1] = (short)f2bf(v0.y);
            pk[2] = (short)f2bf(v0.z); pk[3] = (short)f2bf(v0.w);
            pk[4] = (short)f2bf(v1.x); pk[5] = (short)f2bf(v1.y);
            pk[6] = (short)f2bf(v1.z); pk[7] = (short)f2bf(v1.w);
            *(short8*)&As[(m * 8 + (kc ^ (m & 7))) * 8] = pk;
        }
#pragma unroll
        for (int r = 0; r < 4; ++r) {
            int id = tid + r * 512;
            int n = id >> 3, kc = id & 7;
            short8 v = *(const short8*)(wT + n * 256 + k0 + kc * 8);
            *(short8*)&Bs[(n * 8 + (kc ^ (n & 7))) * 8] = v;
        }
        __syncthreads();

#pragma unroll
        for (int kk = 0; kk < 2; ++kk) {
            int cpos = kk * 4 + (lane >> 4);
            short8 af[4], bfr[4];
#pragma unroll
            for (int mf = 0; mf < 4; ++mf) {
                int m = wr * 64 + mf * 16 + (lane & 15);
                af[mf] = *(const short8*)&As[(m * 8 + (cpos ^ (m & 7))) * 8];
            }
#pragma unroll
            for (int nf = 0; nf < 4; ++nf) {
                int n = wc * 64 + nf * 16 + (lane & 15);
                bfr[nf] = *(const short8*)&Bs[(n * 8 + (cpos ^ (n & 7))) * 8];
            }
#pragma unroll
            for (int mf = 0; mf < 4; ++mf)
#pragma unroll
                for (int nf = 0; nf < 4; ++nf)
                    acc[mf][nf] = __builtin_amdgcn_mfma_f32_16x16x32_bf16(
                        af[mf], bfr[nf], acc[mf][nf], 0, 0, 0);
        }
    }

#pragma unroll
    for (int mf = 0; mf < 4; ++mf)
#pragma unroll
        for (int i = 0; i < 4; ++i) {
            int row = rowBase + wr * 64 + mf * 16 + ((lane >> 4) << 2) + i;
            if (row < N) {
                float dv = dinv[row];
#pragma unroll
                for (int nf = 0; nf < 4; ++nf) {
                    int pc = wc * 64 + nf * 16 + (lane & 15);
                    y[((size_t)(pc >> 5) * N + row) * 32 + (pc & 31)] =
                        f2bf(acc[mf][nf][i] * dv);
                }
            }
        }
}

// ---------- Sliced gather: slice = blockIdx.x & 7 -> XCD-pinned 6.4 MB working set ----------
// Wave per node; 8 edge slots (t=lane>>3) x 8-B col groups (g=lane&7, 4 cols each).
__global__ __launch_bounds__(256) void gather_kernel(const ushort* __restrict__ y,
                                                     const int* __restrict__ off,
                                                     const int* __restrict__ csr,
                                                     const float* __restrict__ pb,
                                                     ushort* __restrict__ f, int N) {
    int tid = threadIdx.x;
    int lane = tid & 63, wid = tid >> 6;
    int s = blockIdx.x & 7;
    int g = lane & 7;
    int t = lane >> 3;
    const ushort* ys = y + (size_t)s * N * 32;
    float4 b4 = *(const float4*)&pb[s * 32 + g * 4];
    int n = (blockIdx.x >> 3) * 4 + wid;
    int stride = (gridDim.x >> 3) * 4;

    for (; n < N; n += stride) {
        int e0 = off[n], e1 = off[n + 1];
        int tot = e1 - e0 + 1;   // + self loop
        float a0 = 0.f, a1 = 0.f, a2 = 0.f, a3 = 0.f;
        for (int base = 0; base < tot; base += 64) {
            int rem = tot - base;
            int iters = rem < 64 ? rem : 64;
            int jj = base + lane;
            int e = e0 + jj - 1;
            e = e > e1 - 1 ? e1 - 1 : e;
            e = e < 0 ? 0 : e;
            int sAll = (jj == 0) ? n : csr[e];
            for (int i = 0; i < iters; i += 8) {
                int sidx = __shfl(sAll, i + t);
                float sc = (i + t < iters) ? 1.f : 0.f;
                uint2 v = *(const uint2*)(ys + (size_t)sidx * 32 + g * 4);
                a0 = fmaf(__uint_as_float(v.x << 16), sc, a0);
                a1 = fmaf(__uint_as_float(v.x & 0xffff0000u), sc, a1);
                a2 = fmaf(__uint_as_float(v.y << 16), sc, a2);
                a3 = fmaf(__uint_as_float(v.y & 0xffff0000u), sc, a3);
            }
        }
#pragma unroll
        for (int d = 8; d < 64; d <<= 1) {
            a0 += __shfl_xor(a0, d);
            a1 += __shfl_xor(a1, d);
            a2 += __shfl_xor(a2, d);
            a3 += __shfl_xor(a3, d);
        }
        float dv = rsqrtf((float)tot);
        float r0 = fmaxf(fmaf(a0, dv, b4.x), 0.f);   // homo (even permuted col)
        float r1 = fmaxf(fmaf(a1, dv, b4.y), 0.f);   // het partner
        float r2 = fmaxf(fmaf(a2, dv, b4.z), 0.f);
        float r3 = fmaxf(fmaf(a3, dv, b4.w), 0.f);
        if (t == 0) {
            uint pk = (uint)f2bf(0.5f * (r0 + r1)) | ((uint)f2bf(0.5f * (r2 + r3)) << 16);
            *(uint*)(f + (size_t)n * 128 + s * 16 + g * 2) = pk;
        }
    }
}

// ---------- MFMA MLP: out = relu(f @ Wf + bf) @ Wc + bc ----------
__global__ __launch_bounds__(256) void mlp_kernel(const ushort* __restrict__ f,
                                                  const ushort* __restrict__ WfB,
                                                  const float* __restrict__ bfu,
                                                  const float* __restrict__ Wc,
                                                  const float* __restrict__ bc,
                                                  float* __restrict__ out, int N) {
    int tid = threadIdx.x;
    int lane = tid & 63, wid = tid >> 6;
    int rowBase = blockIdx.x * 64 + wid * 16;
    int col = lane & 15;
    int kg = lane >> 4;

    short8 bfrag[4][4];
#pragma unroll
    for (int nf = 0; nf < 4; ++nf)
#pragma unroll
        for (int kk = 0; kk < 4; ++kk)
            bfrag[nf][kk] = *(const short8*)(WfB + (size_t)(nf * 16 + col) * 128 + kk * 32 + kg * 8);

    float bfv[4], w0[4], w1[4];
#pragma unroll
    for (int nf = 0; nf < 4; ++nf) {
        int c = nf * 16 + col;
        bfv[nf] = bfu[c];
        w0[nf] = Wc[c * 2];
        w1[nf] = Wc[c * 2 + 1];
    }
    float bc0 = bc[0], bc1 = bc[1];

    int r = rowBase + col; if (r >= N) r = N - 1;
    f32x4 acc[4];
#pragma unroll
    for (int nf = 0; nf < 4; ++nf) acc[nf] = (f32x4){0.f, 0.f, 0.f, 0.f};
#pragma unroll
    for (int kk = 0; kk < 4; ++kk) {
        short8 afrag = *(const short8*)(f + (size_t)r * 128 + kk * 32 + kg * 8);
#pragma unroll
        for (int nf = 0; nf < 4; ++nf)
            acc[nf] = __builtin_amdgcn_mfma_f32_16x16x32_bf16(afrag, bfrag[nf][kk], acc[nf], 0, 0, 0);
    }

#pragma unroll
    for (int i = 0; i < 4; ++i) {
        float p0 = 0.f, p1 = 0.f;
#pragma unroll
        for (int nf = 0; nf < 4; ++nf) {
            float t = fmaxf(acc[nf][i] + bfv[nf], 0.f);
            p0 = fmaf(t, w0[nf], p0);
            p1 = fmaf(t, w1[nf], p1);
        }
#pragma unroll
        for (int d = 1; d < 16; d <<= 1) {
            p0 += __shfl_xor(p0, d);
            p1 += __shfl_xor(p1, d);
        }
        int row = rowBase + kg * 4 + i;
        if (col == 0 && row < N)
            *(float2*)(out + (size_t)row * 2) = make_float2(p0 + bc0, p1 + bc1);
    }
}

extern "C" void kernel_launch(void* const* d_in, const int* in_sizes, int n_in,
                              void* d_out, int out_size, void* d_ws, size_t ws_size,
                              hipStream_t stream) {
    const float* x  = (const float*)d_in[0];
    const int*   ei = (const int*)d_in[1];   // [2,E] int32
    const float* Wh = (const float*)d_in[3];
    const float* bh = (const float*)d_in[4];
    const float* Wt = (const float*)d_in[5];
    const float* bt = (const float*)d_in[6];
    const float* Wf = (const float*)d_in[7];
    const float* bf_ = (const float*)d_in[8];
    const float* Wc = (const float*)d_in[9];
    const float* bc = (const float*)d_in[10];
    float* out = (float*)d_out;

    int N = in_sizes[0] / IN_DIM;
    int E = in_sizes[1] / 2;
    int B = (N + 1023) / 1024;   // scan chunks

    char* w = (char*)d_ws;
    ushort* y   = (ushort*)w;  w += (size_t)N * IN_DIM * 2;          // 51.2 MB bf16 (sliced)
    ushort* wT  = (ushort*)w;  w += (size_t)256 * 256 * 2;
    ushort* WfB = (ushort*)w;  w += (size_t)64 * 128 * 2;
    ushort* f   = (ushort*)w;  w += (size_t)N * 128 * 2;             // 25.6 MB bf16
    float*  pb  = (float*)w;   w += 256 * 4;
    float* dinv = (float*)w;   w += (size_t)N * 4;
    int*   cnt  = (int*)w;     w += (size_t)N * 4;
    int*   off  = (int*)w;     w += (((size_t)(N + 1) * 4) + 15) & ~(size_t)15;
    int*   cur  = (int*)w;     w += (size_t)N * 4;
    int*   bsum = (int*)w;     w += (((size_t)B * 4) + 15) & ~(size_t)15;
    int*   csr  = (int*)w;     w += (size_t)E * 4;

    hipMemsetAsync(cnt, 0, (size_t)N * 4, stream);

    int eb = (E + 255) / 256;
    count_kernel<<<eb, 256, 0, stream>>>(ei + E, cnt, E);
    block_sum_kernel<<<B, 256, 0, stream>>>(cnt, bsum, N);
    scan_sums_kernel<<<1, 1024, 0, stream>>>(bsum, B);
    scan_out_kernel<<<B, 256, 0, stream>>>(cnt, bsum, off, cur, dinv, N, E);
    fill_kernel<<<eb, 256, 0, stream>>>(ei, cur, csr, E);
    wprep_kernel<<<256, 256, 0, stream>>>(Wh, Wt, wT);
    bias_perm_kernel<<<1, 256, 0, stream>>>(bh, bt, pb);
    wfb_kernel<<<64, 128, 0, stream>>>(Wf, WfB);

    gemm_kernel<<<(N + 127) / 128, 512, 0, stream>>>(x, wT, dinv, y, N);
    gather_kernel<<<8192, 256, 0, stream>>>(y, off, csr, pb, f, N);
    mlp_kernel<<<(N + 63) / 64, 256, 0, stream>>>(f, WfB, bf_, Wc, bc, out, N);
}

// Round 6
// 386.980 us; speedup vs baseline: 1.2311x; 1.2311x over previous
//
#include <hip/hip_runtime.h>

#define IN_DIM 256   // K of the fused GEMM; also combined hidden (128 homo + 128 het)

typedef __attribute__((ext_vector_type(8))) short short8;
typedef __attribute__((ext_vector_type(4))) float f32x4;
typedef unsigned int uint;
typedef unsigned short ushort;

__device__ __forceinline__ ushort f2bf(float x) {
    uint u = __float_as_uint(x);
    u += 0x7FFFu + ((u >> 16) & 1u);   // round-to-nearest-even
    return (ushort)(u >> 16);
}

// ---------- CSR build ----------
__global__ void count_kernel(const int* __restrict__ dst, int* __restrict__ cnt, int E) {
    int e = blockIdx.x * 256 + threadIdx.x;
    if (e < E) atomicAdd(&cnt[dst[e]], 1);
}

__global__ __launch_bounds__(256) void block_sum_kernel(const int* __restrict__ cnt,
                                                        int* __restrict__ bsum, int N) {
    __shared__ int red[256];
    int base = blockIdx.x * 1024;
    int s = 0;
    for (int i = threadIdx.x; i < 1024; i += 256) {
        int idx = base + i;
        if (idx < N) s += cnt[idx];
    }
    red[threadIdx.x] = s;
    __syncthreads();
    for (int d = 128; d > 0; d >>= 1) {
        if (threadIdx.x < d) red[threadIdx.x] += red[threadIdx.x + d];
        __syncthreads();
    }
    if (threadIdx.x == 0) bsum[blockIdx.x] = red[0];
}

__global__ __launch_bounds__(1024) void scan_sums_kernel(int* __restrict__ bsum, int B) {
    __shared__ int sh[1024];
    int t = threadIdx.x;
    sh[t] = (t < B) ? bsum[t] : 0;
    __syncthreads();
    for (int d = 1; d < 1024; d <<= 1) {
        int v = (t >= d) ? sh[t - d] : 0;
        __syncthreads();
        sh[t] += v;
        __syncthreads();
    }
    if (t < B) bsum[t] = (t == 0) ? 0 : sh[t - 1];
}

// Phase 3: offsets + cur(=off copy, for fill) + dinv
__global__ __launch_bounds__(256) void scan_out_kernel(const int* __restrict__ cnt,
                                                       const int* __restrict__ bsum,
                                                       int* __restrict__ off,
                                                       int* __restrict__ cur,
                                                       float* __restrict__ dinv,
                                                       int N, int E) {
    __shared__ int wsum[4];
    int lane = threadIdx.x & 63, wid = threadIdx.x >> 6;
    int idx = blockIdx.x * 1024 + threadIdx.x * 4;
    int c[4];
    int s = 0;
#pragma unroll
    for (int j = 0; j < 4; ++j) {
        c[j] = (idx + j < N) ? cnt[idx + j] : 0;
        s += c[j];
    }
    int incl = s;
#pragma unroll
    for (int d = 1; d < 64; d <<= 1) {
        int v = __shfl_up(incl, d);
        if (lane >= d) incl += v;
    }
    if (lane == 63) wsum[wid] = incl;
    __syncthreads();
    int woff = 0;
    for (int i = 0; i < 4; ++i) woff += (i < wid) ? wsum[i] : 0;
    int excl = bsum[blockIdx.x] + woff + incl - s;
#pragma unroll
    for (int j = 0; j < 4; ++j) {
        if (idx + j < N) {
            off[idx + j] = excl;
            cur[idx + j] = excl;
            dinv[idx + j] = rsqrtf((float)(c[j] + 1));  // +1 self loop
        }
        excl += c[j];
    }
    if (blockIdx.x == 0 && threadIdx.x == 0) off[N] = E;
}

// fill: cur pre-initialized to off -> atomic returns the csr slot directly
__global__ void fill_kernel(const int* __restrict__ ei, int* __restrict__ cur,
                            int* __restrict__ csr, int E) {
    int e = blockIdx.x * 256 + threadIdx.x;
    if (e < E) {
        int s = ei[e];
        int d = ei[E + e];
        int p = atomicAdd(&cur[d], 1);
        csr[p] = s;
    }
}

// ---------- merged W prep ----------
// blocks 0..255: wT[c][k] = bf16(W*[k][c])  (c<128 homo, else het)
// blocks 256..319: WfB[col][k] = bf16(Wf[k][col])
__global__ void prep_kernel(const float* __restrict__ Wh, const float* __restrict__ Wt,
                            const float* __restrict__ Wf,
                            ushort* __restrict__ wT, ushort* __restrict__ WfB) {
    int b = blockIdx.x;
    int k = threadIdx.x;
    if (b < 256) {
        const float* W = (b < 128) ? Wh : Wt;
        wT[b * 256 + k] = f2bf(W[(size_t)k * 128 + (b & 127)]);
    } else {
        int col = b - 256;
        if (k < 128) WfB[col * 128 + k] = f2bf(Wf[(size_t)k * 64 + col]);
    }
}

// ---------- MFMA GEMM: y[n][c] = bf16( (x[n] @ [Wh|Wt])[c] * dinv[n] ) ----------
__global__ __launch_bounds__(512) void gemm_kernel(const float* __restrict__ x,
                                                   const ushort* __restrict__ wT,
                                                   const float* __restrict__ dinv,
                                                   ushort* __restrict__ y, int N) {
    __shared__ short As[128 * 64];   // 16 KB
    __shared__ short Bs[256 * 64];   // 32 KB
    int tid = threadIdx.x;
    int lane = tid & 63, wid = tid >> 6;
    int wr = wid >> 2, wc = wid & 3;
    int rowBase = blockIdx.x * 128;

    f32x4 acc[4][4];
#pragma unroll
    for (int a = 0; a < 4; ++a)
#pragma unroll
        for (int b = 0; b < 4; ++b) acc[a][b] = (f32x4){0.f, 0.f, 0.f, 0.f};

    for (int k0 = 0; k0 < IN_DIM; k0 += 64) {
        __syncthreads();
#pragma unroll
        for (int r = 0; r < 2; ++r) {
            int id = tid + r * 512;
            int m = id >> 3, kc = id & 7;
            int gr = rowBase + m; if (gr >= N) gr = N - 1;
            const float* src = x + (size_t)gr * IN_DIM + k0 + kc * 8;
            float4 v0 = *(const float4*)src;
            float4 v1 = *(const float4*)(src + 4);
            short8 pk;
            pk[0] = (short)f2bf(v0.x); pk[1] = (short)f2bf(v0.y);
            pk[2] = (short)f2bf(v0.z); pk[3] = (short)f2bf(v0.w);
            pk[4] = (short)f2bf(v1.x); pk[5] = (short)f2bf(v1.y);
            pk[6] = (short)f2bf(v1.z); pk[7] = (short)f2bf(v1.w);
            *(short8*)&As[(m * 8 + (kc ^ (m & 7))) * 8] = pk;
        }
#pragma unroll
        for (int r = 0; r < 4; ++r) {
            int id = tid + r * 512;
            int n = id >> 3, kc = id & 7;
            short8 v = *(const short8*)(wT + n * 256 + k0 + kc * 8);
            *(short8*)&Bs[(n * 8 + (kc ^ (n & 7))) * 8] = v;
        }
        __syncthreads();

#pragma unroll
        for (int kk = 0; kk < 2; ++kk) {
            int cpos = kk * 4 + (lane >> 4);
            short8 af[4], bfr[4];
#pragma unroll
            for (int mf = 0; mf < 4; ++mf) {
                int m = wr * 64 + mf * 16 + (lane & 15);
                af[mf] = *(const short8*)&As[(m * 8 + (cpos ^ (m & 7))) * 8];
            }
#pragma unroll
            for (int nf = 0; nf < 4; ++nf) {
                int n = wc * 64 + nf * 16 + (lane & 15);
                bfr[nf] = *(const short8*)&Bs[(n * 8 + (cpos ^ (n & 7))) * 8];
            }
#pragma unroll
            for (int mf = 0; mf < 4; ++mf)
#pragma unroll
                for (int nf = 0; nf < 4; ++nf)
                    acc[mf][nf] = __builtin_amdgcn_mfma_f32_16x16x32_bf16(
                        af[mf], bfr[nf], acc[mf][nf], 0, 0, 0);
        }
    }

#pragma unroll
    for (int mf = 0; mf < 4; ++mf)
#pragma unroll
        for (int i = 0; i < 4; ++i) {
            int row = rowBase + wr * 64 + mf * 16 + ((lane >> 4) << 2) + i;
            if (row < N) {
                float dv = dinv[row];
#pragma unroll
                for (int nf = 0; nf < 4; ++nf)
                    y[(size_t)row * IN_DIM + wc * 64 + nf * 16 + (lane & 15)] =
                        f2bf(acc[mf][nf][i] * dv);
            }
        }
}

// ---------- Gather (wave-per-node; whole-wave 512B rows; 8 edges in flight) ----------
// Lane owns 4 dims: c = lane*4+j. Virtual edge 0 = self loop. Edge indices fetched
// coalesced once per 64-window, broadcast via uniform readlane -> SGPR addressing.
__global__ __launch_bounds__(256) void gather_kernel(const ushort* __restrict__ y,
                                                     const int* __restrict__ off,
                                                     const int* __restrict__ csr,
                                                     const float* __restrict__ bh,
                                                     const float* __restrict__ bt,
                                                     ushort* __restrict__ f, int N) {
    int tid = threadIdx.x;
    int lane = tid & 63, wid = tid >> 6;
    const float* bp = (lane < 32) ? (bh + lane * 4) : (bt + (lane - 32) * 4);
    float4 b4 = *(const float4*)bp;
    int n = blockIdx.x * 4 + wid;
    int stride = gridDim.x * 4;

    for (; n < N; n += stride) {
        int e0 = off[n], e1 = off[n + 1];
        int tot = e1 - e0 + 1;   // + self loop (virtual edge 0)
        float a0 = 0.f, a1 = 0.f, a2 = 0.f, a3 = 0.f;
        for (int base = 0; base < tot; base += 64) {
            int rem = tot - base;
            int iters = rem < 64 ? rem : 64;
            int jj = base + lane;
            int cj = jj < tot - 1 ? jj : tot - 1;
            int sAll = (cj == 0) ? n : csr[e0 + cj - 1];
            int full = iters & ~7;
            int i = 0;
            for (; i < full; i += 8) {   // unmasked fast path: 8 rows in flight
                int s[8];
#pragma unroll
                for (int k = 0; k < 8; ++k) s[k] = __builtin_amdgcn_readlane(sAll, i + k);
                uint2 v[8];
#pragma unroll
                for (int k = 0; k < 8; ++k)
                    v[k] = *(const uint2*)(y + (size_t)s[k] * 256 + lane * 4);
#pragma unroll
                for (int k = 0; k < 8; ++k) {
                    a0 += __uint_as_float(v[k].x << 16);
                    a1 += __uint_as_float(v[k].x & 0xffff0000u);
                    a2 += __uint_as_float(v[k].y << 16);
                    a3 += __uint_as_float(v[k].y & 0xffff0000u);
                }
            }
            if (i < iters) {             // one masked tail group
                int s[8];
                float sc[8];
#pragma unroll
                for (int k = 0; k < 8; ++k) {
                    int j = i + k;
                    int cjj = j < iters - 1 ? j : iters - 1;
                    s[k] = __builtin_amdgcn_readlane(sAll, cjj);
                    sc[k] = (j < iters) ? 1.f : 0.f;
                }
                uint2 v[8];
#pragma unroll
                for (int k = 0; k < 8; ++k)
                    v[k] = *(const uint2*)(y + (size_t)s[k] * 256 + lane * 4);
#pragma unroll
                for (int k = 0; k < 8; ++k) {
                    a0 = fmaf(__uint_as_float(v[k].x << 16), sc[k], a0);
                    a1 = fmaf(__uint_as_float(v[k].x & 0xffff0000u), sc[k], a1);
                    a2 = fmaf(__uint_as_float(v[k].y << 16), sc[k], a2);
                    a3 = fmaf(__uint_as_float(v[k].y & 0xffff0000u), sc[k], a3);
                }
            }
        }
        float dv = rsqrtf((float)tot);
        float r0 = fmaxf(fmaf(a0, dv, b4.x), 0.f);
        float r1 = fmaxf(fmaf(a1, dv, b4.y), 0.f);
        float r2 = fmaxf(fmaf(a2, dv, b4.z), 0.f);
        float r3 = fmaxf(fmaf(a3, dv, b4.w), 0.f);
        float o0 = __shfl_xor(r0, 32);
        float o1 = __shfl_xor(r1, 32);
        float o2 = __shfl_xor(r2, 32);
        float o3 = __shfl_xor(r3, 32);
        if (lane < 32) {
            float h0 = 0.5f * (r0 + o0);
            float h1 = 0.5f * (r1 + o1);
            float h2 = 0.5f * (r2 + o2);
            float h3 = 0.5f * (r3 + o3);
            uint2 pk;
            pk.x = (uint)f2bf(h0) | ((uint)f2bf(h1) << 16);
            pk.y = (uint)f2bf(h2) | ((uint)f2bf(h3) << 16);
            *(uint2*)(f + (size_t)n * 128 + lane * 4) = pk;
        }
    }
}

// ---------- MFMA MLP: out = relu(f @ Wf + bf) @ Wc + bc ----------
__global__ __launch_bounds__(256) void mlp_kernel(const ushort* __restrict__ f,
                                                  const ushort* __restrict__ WfB,
                                                  const float* __restrict__ bfu,
                                                  const float* __restrict__ Wc,
                                                  const float* __restrict__ bc,
                                                  float* __restrict__ out, int N) {
    int tid = threadIdx.x;
    int lane = tid & 63, wid = tid >> 6;
    int rowBase = blockIdx.x * 64 + wid * 16;
    int col = lane & 15;
    int kg = lane >> 4;

    short8 bfrag[4][4];
#pragma unroll
    for (int nf = 0; nf < 4; ++nf)
#pragma unroll
        for (int kk = 0; kk < 4; ++kk)
            bfrag[nf][kk] = *(const short8*)(WfB + (size_t)(nf * 16 + col) * 128 + kk * 32 + kg * 8);

    float bfv[4], w0[4], w1[4];
#pragma unroll
    for (int nf = 0; nf < 4; ++nf) {
        int c = nf * 16 + col;
        bfv[nf] = bfu[c];
        w0[nf] = Wc[c * 2];
        w1[nf] = Wc[c * 2 + 1];
    }
    float bc0 = bc[0], bc1 = bc[1];

    int r = rowBase + col; if (r >= N) r = N - 1;
    f32x4 acc[4];
#pragma unroll
    for (int nf = 0; nf < 4; ++nf) acc[nf] = (f32x4){0.f, 0.f, 0.f, 0.f};
#pragma unroll
    for (int kk = 0; kk < 4; ++kk) {
        short8 afrag = *(const short8*)(f + (size_t)r * 128 + kk * 32 + kg * 8);
#pragma unroll
        for (int nf = 0; nf < 4; ++nf)
            acc[nf] = __builtin_amdgcn_mfma_f32_16x16x32_bf16(afrag, bfrag[nf][kk], acc[nf], 0, 0, 0);
    }

#pragma unroll
    for (int i = 0; i < 4; ++i) {
        float p0 = 0.f, p1 = 0.f;
#pragma unroll
        for (int nf = 0; nf < 4; ++nf) {
            float t = fmaxf(acc[nf][i] + bfv[nf], 0.f);
            p0 = fmaf(t, w0[nf], p0);
            p1 = fmaf(t, w1[nf], p1);
        }
#pragma unroll
        for (int d = 1; d < 16; d <<= 1) {
            p0 += __shfl_xor(p0, d);
            p1 += __shfl_xor(p1, d);
        }
        int row = rowBase + kg * 4 + i;
        if (col == 0 && row < N)
            *(float2*)(out + (size_t)row * 2) = make_float2(p0 + bc0, p1 + bc1);
    }
}

extern "C" void kernel_launch(void* const* d_in, const int* in_sizes, int n_in,
                              void* d_out, int out_size, void* d_ws, size_t ws_size,
                              hipStream_t stream) {
    const float* x  = (const float*)d_in[0];
    const int*   ei = (const int*)d_in[1];   // [2,E] int32
    const float* Wh = (const float*)d_in[3];
    const float* bh = (const float*)d_in[4];
    const float* Wt = (const float*)d_in[5];
    const float* bt = (const float*)d_in[6];
    const float* Wf = (const float*)d_in[7];
    const float* bf_ = (const float*)d_in[8];
    const float* Wc = (const float*)d_in[9];
    const float* bc = (const float*)d_in[10];
    float* out = (float*)d_out;

    int N = in_sizes[0] / IN_DIM;
    int E = in_sizes[1] / 2;
    int B = (N + 1023) / 1024;   // scan chunks

    char* w = (char*)d_ws;
    ushort* y   = (ushort*)w;  w += (size_t)N * IN_DIM * 2;          // 51.2 MB bf16
    ushort* wT  = (ushort*)w;  w += (size_t)256 * 256 * 2;
    ushort* WfB = (ushort*)w;  w += (size_t)64 * 128 * 2;
    ushort* f   = (ushort*)w;  w += (size_t)N * 128 * 2;             // 25.6 MB bf16
    float* dinv = (float*)w;   w += (size_t)N * 4;
    int*   cnt  = (int*)w;     w += (size_t)N * 4;
    int*   off  = (int*)w;     w += (((size_t)(N + 1) * 4) + 15) & ~(size_t)15;
    int*   cur  = (int*)w;     w += (size_t)N * 4;
    int*   bsum = (int*)w;     w += (((size_t)B * 4) + 15) & ~(size_t)15;
    int*   csr  = (int*)w;     w += (size_t)E * 4;

    hipMemsetAsync(cnt, 0, (size_t)N * 4, stream);

    int eb = (E + 255) / 256;
    count_kernel<<<eb, 256, 0, stream>>>(ei + E, cnt, E);
    block_sum_kernel<<<B, 256, 0, stream>>>(cnt, bsum, N);
    scan_sums_kernel<<<1, 1024, 0, stream>>>(bsum, B);
    scan_out_kernel<<<B, 256, 0, stream>>>(cnt, bsum, off, cur, dinv, N, E);
    fill_kernel<<<eb, 256, 0, stream>>>(ei, cur, csr, E);
    prep_kernel<<<320, 256, 0, stream>>>(Wh, Wt, Wf, wT, WfB);

    gemm_kernel<<<(N + 127) / 128, 512, 0, stream>>>(x, wT, dinv, y, N);
    gather_kernel<<<2048, 256, 0, stream>>>(y, off, csr, bh, bt, f, N);
    mlp_kernel<<<(N + 63) / 64, 256, 0, stream>>>(f, WfB, bf_, Wc, bc, out, N);
}

// Round 7
// 229.630 us; speedup vs baseline: 2.0747x; 1.6852x over previous
//
#include <hip/hip_runtime.h>

#define IN_DIM 256
#define CHUNK 8192          // edges per hist/scatter block
#define NBUCKET 1024        // dst buckets (128 nodes each)

typedef __attribute__((ext_vector_type(8))) short short8;
typedef __attribute__((ext_vector_type(4))) float f32x4;
typedef unsigned int uint;
typedef unsigned short ushort;

__device__ __forceinline__ ushort f2bf(float x) {
    uint u = __float_as_uint(x);
    u += 0x7FFFu + ((u >> 16) & 1u);   // round-to-nearest-even
    return (ushort)(u >> 16);
}

// ---------- CSR build via counting sort ----------
// Pass A: per-(bucket, block) histogram. bucket = dst >> 7.
__global__ __launch_bounds__(256) void hist_kernel(const int* __restrict__ dst,
                                                   int* __restrict__ hist_g,
                                                   int E, int NBLK) {
    __shared__ int h[NBUCKET];
    int tid = threadIdx.x;
#pragma unroll
    for (int i = 0; i < 4; ++i) h[tid + 256 * i] = 0;
    __syncthreads();
    int base = blockIdx.x * CHUNK;
#pragma unroll 4
    for (int i = 0; i < 32; ++i) {
        int e = base + i * 256 + tid;
        if (e < E) atomicAdd(&h[dst[e] >> 7], 1);
    }
    __syncthreads();
#pragma unroll
    for (int i = 0; i < 4; ++i) {
        int b = tid + 256 * i;
        hist_g[(size_t)b * NBLK + blockIdx.x] = h[b];
    }
}

// Generic hierarchical exclusive scan over L = NBUCKET*NBLK ints (bucket-major).
__global__ __launch_bounds__(256) void block_sum_kernel(const int* __restrict__ d,
                                                        int* __restrict__ bsum, int L) {
    __shared__ int red[256];
    int base = blockIdx.x * 1024;
    int s = 0;
    for (int i = threadIdx.x; i < 1024; i += 256) {
        int idx = base + i;
        if (idx < L) s += d[idx];
    }
    red[threadIdx.x] = s;
    __syncthreads();
    for (int dd = 128; dd > 0; dd >>= 1) {
        if (threadIdx.x < dd) red[threadIdx.x] += red[threadIdx.x + dd];
        __syncthreads();
    }
    if (threadIdx.x == 0) bsum[blockIdx.x] = red[0];
}

__global__ __launch_bounds__(1024) void scan_sums_kernel(int* __restrict__ bsum, int B) {
    __shared__ int sh[1024];
    int t = threadIdx.x;
    sh[t] = (t < B) ? bsum[t] : 0;
    __syncthreads();
    for (int d = 1; d < 1024; d <<= 1) {
        int v = (t >= d) ? sh[t - d] : 0;
        __syncthreads();
        sh[t] += v;
        __syncthreads();
    }
    if (t < B) bsum[t] = (t == 0) ? 0 : sh[t - 1];
}

__global__ __launch_bounds__(256) void scan_apply_kernel(int* __restrict__ d,
                                                         const int* __restrict__ bsum, int L) {
    __shared__ int wsum[4];
    int lane = threadIdx.x & 63, wid = threadIdx.x >> 6;
    int idx = blockIdx.x * 1024 + threadIdx.x * 4;
    int c[4];
    int s = 0;
#pragma unroll
    for (int j = 0; j < 4; ++j) {
        c[j] = (idx + j < L) ? d[idx + j] : 0;
        s += c[j];
    }
    int incl = s;
#pragma unroll
    for (int dd = 1; dd < 64; dd <<= 1) {
        int v = __shfl_up(incl, dd);
        if (lane >= dd) incl += v;
    }
    if (lane == 63) wsum[wid] = incl;
    __syncthreads();
    int woff = 0;
    for (int i = 0; i < 4; ++i) woff += (i < wid) ? wsum[i] : 0;
    int excl = bsum[blockIdx.x] + woff + incl - s;
#pragma unroll
    for (int j = 0; j < 4; ++j) {
        if (idx + j < L) d[idx + j] = excl;
        excl += c[j];
    }
}

// Pass B: scatter edges bucket-sorted as (src,dst) pairs.
__global__ __launch_bounds__(256) void scatter_kernel(const int* __restrict__ ei,
                                                      const int* __restrict__ scanned,
                                                      uint2* __restrict__ sorted,
                                                      int E, int NBLK) {
    __shared__ int baseh[NBUCKET];
    __shared__ int curh[NBUCKET];
    int tid = threadIdx.x;
#pragma unroll
    for (int i = 0; i < 4; ++i) {
        int b = tid + 256 * i;
        baseh[b] = scanned[(size_t)b * NBLK + blockIdx.x];
        curh[b] = 0;
    }
    __syncthreads();
    int base = blockIdx.x * CHUNK;
#pragma unroll 4
    for (int i = 0; i < 32; ++i) {
        int e = base + i * 256 + tid;
        if (e < E) {
            int s = ei[e];
            int d = ei[E + e];
            int b = d >> 7;
            int r = atomicAdd(&curh[b], 1);
            sorted[baseh[b] + r] = make_uint2((uint)s, (uint)d);
        }
    }
}

// Pass C: per-bucket CSR in LDS -> dense csr/off/dinv.
__global__ __launch_bounds__(256) void bucket_csr_kernel(const uint2* __restrict__ sorted,
                                                         const int* __restrict__ scanned,
                                                         int* __restrict__ off,
                                                         int* __restrict__ csr,
                                                         float* __restrict__ dinv,
                                                         int N, int E, int NBLK) {
    __shared__ int cnt[128], cur[128];
    __shared__ int w0tot;
    int b = blockIdx.x;
    int tid = threadIdx.x;
    int estart = scanned[(size_t)b * NBLK];
    int eend = scanned[(size_t)(b + 1) * NBLK];   // b+1 <= 782 < NBUCKET
    if (tid < 128) cnt[tid] = 0;
    __syncthreads();
    for (int e = estart + tid; e < eend; e += 256)
        atomicAdd(&cnt[sorted[e].y & 127], 1);
    __syncthreads();
    int c = 0, incl = 0;
    if (tid < 128) {
        int lane = tid & 63;
        c = cnt[tid];
        incl = c;
#pragma unroll
        for (int d = 1; d < 64; d <<= 1) {
            int v = __shfl_up(incl, d);
            if (lane >= d) incl += v;
        }
        if (tid == 63) w0tot = incl;
    }
    __syncthreads();
    if (tid < 128) {
        int e0 = incl - c + ((tid >= 64) ? w0tot : 0);
        cur[tid] = e0;
        int node = b * 128 + tid;
        if (node < N) {
            off[node] = estart + e0;
            dinv[node] = rsqrtf((float)(c + 1));   // +1 self loop
        }
    }
    if (b == 0 && tid == 0) off[N] = E;
    __syncthreads();
    for (int e = estart + tid; e < eend; e += 256) {
        uint2 sd = sorted[e];
        int pos = atomicAdd(&cur[sd.y & 127], 1);
        csr[estart + pos] = (int)sd.x;
    }
}

// ---------- merged W prep ----------
__global__ void prep_kernel(const float* __restrict__ Wh, const float* __restrict__ Wt,
                            const float* __restrict__ Wf,
                            ushort* __restrict__ wT, ushort* __restrict__ WfB) {
    int b = blockIdx.x;
    int k = threadIdx.x;
    if (b < 256) {
        const float* W = (b < 128) ? Wh : Wt;
        wT[b * 256 + k] = f2bf(W[(size_t)k * 128 + (b & 127)]);
    } else {
        int col = b - 256;
        if (k < 128) WfB[col * 128 + k] = f2bf(Wf[(size_t)k * 64 + col]);
    }
}

// ---------- MFMA GEMM: y[n][c] = bf16( (x[n] @ [Wh|Wt])[c] * dinv[n] ) ----------
__global__ __launch_bounds__(512) void gemm_kernel(const float* __restrict__ x,
                                                   const ushort* __restrict__ wT,
                                                   const float* __restrict__ dinv,
                                                   ushort* __restrict__ y, int N) {
    __shared__ short As[128 * 64];   // 16 KB
    __shared__ short Bs[256 * 64];   // 32 KB
    int tid = threadIdx.x;
    int lane = tid & 63, wid = tid >> 6;
    int wr = wid >> 2, wc = wid & 3;
    int rowBase = blockIdx.x * 128;

    f32x4 acc[4][4];
#pragma unroll
    for (int a = 0; a < 4; ++a)
#pragma unroll
        for (int b = 0; b < 4; ++b) acc[a][b] = (f32x4){0.f, 0.f, 0.f, 0.f};

    for (int k0 = 0; k0 < IN_DIM; k0 += 64) {
        __syncthreads();
#pragma unroll
        for (int r = 0; r < 2; ++r) {
            int id = tid + r * 512;
            int m = id >> 3, kc = id & 7;
            int gr = rowBase + m; if (gr >= N) gr = N - 1;
            const float* src = x + (size_t)gr * IN_DIM + k0 + kc * 8;
            float4 v0 = *(const float4*)src;
            float4 v1 = *(const float4*)(src + 4);
            short8 pk;
            pk[0] = (short)f2bf(v0.x); pk[1] = (short)f2bf(v0.y);
            pk[2] = (short)f2bf(v0.z); pk[3] = (short)f2bf(v0.w);
            pk[4] = (short)f2bf(v1.x); pk[5] = (short)f2bf(v1.y);
            pk[6] = (short)f2bf(v1.z); pk[7] = (short)f2bf(v1.w);
            *(short8*)&As[(m * 8 + (kc ^ (m & 7))) * 8] = pk;
        }
#pragma unroll
        for (int r = 0; r < 4; ++r) {
            int id = tid + r * 512;
            int n = id >> 3, kc = id & 7;
            short8 v = *(const short8*)(wT + n * 256 + k0 + kc * 8);
            *(short8*)&Bs[(n * 8 + (kc ^ (n & 7))) * 8] = v;
        }
        __syncthreads();

#pragma unroll
        for (int kk = 0; kk < 2; ++kk) {
            int cpos = kk * 4 + (lane >> 4);
            short8 af[4], bfr[4];
#pragma unroll
            for (int mf = 0; mf < 4; ++mf) {
                int m = wr * 64 + mf * 16 + (lane & 15);
                af[mf] = *(const short8*)&As[(m * 8 + (cpos ^ (m & 7))) * 8];
            }
#pragma unroll
            for (int nf = 0; nf < 4; ++nf) {
                int n = wc * 64 + nf * 16 + (lane & 15);
                bfr[nf] = *(const short8*)&Bs[(n * 8 + (cpos ^ (n & 7))) * 8];
            }
#pragma unroll
            for (int mf = 0; mf < 4; ++mf)
#pragma unroll
                for (int nf = 0; nf < 4; ++nf)
                    acc[mf][nf] = __builtin_amdgcn_mfma_f32_16x16x32_bf16(
                        af[mf], bfr[nf], acc[mf][nf], 0, 0, 0);
        }
    }

#pragma unroll
    for (int mf = 0; mf < 4; ++mf)
#pragma unroll
        for (int i = 0; i < 4; ++i) {
            int row = rowBase + wr * 64 + mf * 16 + ((lane >> 4) << 2) + i;
            if (row < N) {
                float dv = dinv[row];
#pragma unroll
                for (int nf = 0; nf < 4; ++nf)
                    y[(size_t)row * IN_DIM + wc * 64 + nf * 16 + (lane & 15)] =
                        f2bf(acc[mf][nf][i] * dv);
            }
        }
}

// ---------- Gather (round-4 form: wave-per-node, 4 edges in flight) ----------
__global__ __launch_bounds__(256) void gather_kernel(const ushort* __restrict__ y,
                                                     const int* __restrict__ off,
                                                     const int* __restrict__ csr,
                                                     const float* __restrict__ bh,
                                                     const float* __restrict__ bt,
                                                     ushort* __restrict__ f, int N) {
    int tid = threadIdx.x;
    int lane = tid & 63, wid = tid >> 6;
    const float* bp = (lane < 32) ? (bh + lane * 4) : (bt + (lane - 32) * 4);
    float4 b4 = *(const float4*)bp;
    int n = blockIdx.x * 4 + wid;
    int stride = gridDim.x * 4;

    for (; n < N; n += stride) {
        int e0 = off[n], e1 = off[n + 1];
        int deg = e1 - e0;
        float a0, a1, a2, a3;
        {   // self-loop row
            uint2 sv = *(const uint2*)(y + (size_t)n * 256 + lane * 4);
            a0 = __uint_as_float(sv.x << 16);
            a1 = __uint_as_float(sv.x & 0xffff0000u);
            a2 = __uint_as_float(sv.y << 16);
            a3 = __uint_as_float(sv.y & 0xffff0000u);
        }
        for (int base = 0; base < deg; base += 64) {
            int rem = deg - base;
            int iters = rem < 64 ? rem : 64;
            int sAll = csr[e0 + base + (lane < iters ? lane : iters - 1)];
            for (int i = 0; i < iters; i += 4) {
                int idx[4], s[4];
                float sc[4];
#pragma unroll
                for (int k = 0; k < 4; ++k) {
                    idx[k] = (i + k < iters) ? i + k : iters - 1;
                    sc[k] = (i + k < iters) ? 1.f : 0.f;
                }
#pragma unroll
                for (int k = 0; k < 4; ++k) s[k] = __builtin_amdgcn_readlane(sAll, idx[k]);
                uint2 v[4];
#pragma unroll
                for (int k = 0; k < 4; ++k)
                    v[k] = *(const uint2*)(y + (size_t)s[k] * 256 + lane * 4);
                a0 += __uint_as_float(v[0].x << 16);
                a1 += __uint_as_float(v[0].x & 0xffff0000u);
                a2 += __uint_as_float(v[0].y << 16);
                a3 += __uint_as_float(v[0].y & 0xffff0000u);
#pragma unroll
                for (int k = 1; k < 4; ++k) {
                    a0 = fmaf(__uint_as_float(v[k].x << 16), sc[k], a0);
                    a1 = fmaf(__uint_as_float(v[k].x & 0xffff0000u), sc[k], a1);
                    a2 = fmaf(__uint_as_float(v[k].y << 16), sc[k], a2);
                    a3 = fmaf(__uint_as_float(v[k].y & 0xffff0000u), sc[k], a3);
                }
            }
        }
        float dv = rsqrtf((float)(deg + 1));
        float r0 = fmaxf(fmaf(a0, dv, b4.x), 0.f);
        float r1 = fmaxf(fmaf(a1, dv, b4.y), 0.f);
        float r2 = fmaxf(fmaf(a2, dv, b4.z), 0.f);
        float r3 = fmaxf(fmaf(a3, dv, b4.w), 0.f);
        float o0 = __shfl_xor(r0, 32);
        float o1 = __shfl_xor(r1, 32);
        float o2 = __shfl_xor(r2, 32);
        float o3 = __shfl_xor(r3, 32);
        if (lane < 32) {
            float h0 = 0.5f * (r0 + o0);
            float h1 = 0.5f * (r1 + o1);
            float h2 = 0.5f * (r2 + o2);
            float h3 = 0.5f * (r3 + o3);
            uint2 pk;
            pk.x = (uint)f2bf(h0) | ((uint)f2bf(h1) << 16);
            pk.y = (uint)f2bf(h2) | ((uint)f2bf(h3) << 16);
            *(uint2*)(f + (size_t)n * 128 + lane * 4) = pk;
        }
    }
}

// ---------- MFMA MLP: out = relu(f @ Wf + bf) @ Wc + bc ----------
__global__ __launch_bounds__(256) void mlp_kernel(const ushort* __restrict__ f,
                                                  const ushort* __restrict__ WfB,
                                                  const float* __restrict__ bfu,
                                                  const float* __restrict__ Wc,
                                                  const float* __restrict__ bc,
                                                  float* __restrict__ out, int N) {
    int tid = threadIdx.x;
    int lane = tid & 63, wid = tid >> 6;
    int rowBase = blockIdx.x * 64 + wid * 16;
    int col = lane & 15;
    int kg = lane >> 4;

    short8 bfrag[4][4];
#pragma unroll
    for (int nf = 0; nf < 4; ++nf)
#pragma unroll
        for (int kk = 0; kk < 4; ++kk)
            bfrag[nf][kk] = *(const short8*)(WfB + (size_t)(nf * 16 + col) * 128 + kk * 32 + kg * 8);

    float bfv[4], w0[4], w1[4];
#pragma unroll
    for (int nf = 0; nf < 4; ++nf) {
        int c = nf * 16 + col;
        bfv[nf] = bfu[c];
        w0[nf] = Wc[c * 2];
        w1[nf] = Wc[c * 2 + 1];
    }
    float bc0 = bc[0], bc1 = bc[1];

    int r = rowBase + col; if (r >= N) r = N - 1;
    f32x4 acc[4];
#pragma unroll
    for (int nf = 0; nf < 4; ++nf) acc[nf] = (f32x4){0.f, 0.f, 0.f, 0.f};
#pragma unroll
    for (int kk = 0; kk < 4; ++kk) {
        short8 afrag = *(const short8*)(f + (size_t)r * 128 + kk * 32 + kg * 8);
#pragma unroll
        for (int nf = 0; nf < 4; ++nf)
            acc[nf] = __builtin_amdgcn_mfma_f32_16x16x32_bf16(afrag, bfrag[nf][kk], acc[nf], 0, 0, 0);
    }

#pragma unroll
    for (int i = 0; i < 4; ++i) {
        float p0 = 0.f, p1 = 0.f;
#pragma unroll
        for (int nf = 0; nf < 4; ++nf) {
            float t = fmaxf(acc[nf][i] + bfv[nf], 0.f);
            p0 = fmaf(t, w0[nf], p0);
            p1 = fmaf(t, w1[nf], p1);
        }
#pragma unroll
        for (int d = 1; d < 16; d <<= 1) {
            p0 += __shfl_xor(p0, d);
            p1 += __shfl_xor(p1, d);
        }
        int row = rowBase + kg * 4 + i;
        if (col == 0 && row < N)
            *(float2*)(out + (size_t)row * 2) = make_float2(p0 + bc0, p1 + bc1);
    }
}

extern "C" void kernel_launch(void* const* d_in, const int* in_sizes, int n_in,
                              void* d_out, int out_size, void* d_ws, size_t ws_size,
                              hipStream_t stream) {
    const float* x  = (const float*)d_in[0];
    const int*   ei = (const int*)d_in[1];   // [2,E] int32
    const float* Wh = (const float*)d_in[3];
    const float* bh = (const float*)d_in[4];
    const float* Wt = (const float*)d_in[5];
    const float* bt = (const float*)d_in[6];
    const float* Wf = (const float*)d_in[7];
    const float* bf_ = (const float*)d_in[8];
    const float* Wc = (const float*)d_in[9];
    const float* bc = (const float*)d_in[10];
    float* out = (float*)d_out;

    int N = in_sizes[0] / IN_DIM;
    int E = in_sizes[1] / 2;
    int NBLK = (E + CHUNK - 1) / CHUNK;       // hist/scatter blocks
    int L = NBUCKET * NBLK;                   // scan length
    int SB = (L + 1023) / 1024;               // scan chunks (== NBLK)
    int NBKT = (N + 127) / 128;               // active buckets

    char* w = (char*)d_ws;
    ushort* y    = (ushort*)w;  w += (size_t)N * IN_DIM * 2;         // 51.2 MB
    ushort* wT   = (ushort*)w;  w += (size_t)256 * 256 * 2;
    ushort* WfB  = (ushort*)w;  w += (size_t)64 * 128 * 2;
    ushort* f    = (ushort*)w;  w += (size_t)N * 128 * 2;            // 25.6 MB
    float* dinv  = (float*)w;   w += (size_t)N * 4;
    int*   off   = (int*)w;     w += (((size_t)(N + 1) * 4) + 15) & ~(size_t)15;
    int*   hist  = (int*)w;     w += (((size_t)L * 4) + 15) & ~(size_t)15;       // 0.8 MB
    int*   bsum  = (int*)w;     w += (((size_t)SB * 4) + 15) & ~(size_t)15;
    uint2* sorted = (uint2*)w;  w += (size_t)E * 8;                  // 12.8 MB
    int*   csr   = (int*)w;     w += (size_t)E * 4;                  // 6.4 MB

    hist_kernel<<<NBLK, 256, 0, stream>>>(ei + E, hist, E, NBLK);
    block_sum_kernel<<<SB, 256, 0, stream>>>(hist, bsum, L);
    scan_sums_kernel<<<1, 1024, 0, stream>>>(bsum, SB);
    scan_apply_kernel<<<SB, 256, 0, stream>>>(hist, bsum, L);
    scatter_kernel<<<NBLK, 256, 0, stream>>>(ei, hist, sorted, E, NBLK);
    bucket_csr_kernel<<<NBKT, 256, 0, stream>>>(sorted, hist, off, csr, dinv, N, E, NBLK);
    prep_kernel<<<320, 256, 0, stream>>>(Wh, Wt, Wf, wT, WfB);

    gemm_kernel<<<(N + 127) / 128, 512, 0, stream>>>(x, wT, dinv, y, N);
    gather_kernel<<<2048, 256, 0, stream>>>(y, off, csr, bh, bt, f, N);
    mlp_kernel<<<(N + 63) / 64, 256, 0, stream>>>(f, WfB, bf_, Wc, bc, out, N);
}